// Round 1
// baseline (3335.594 us; speedup 1.0000x reference)
//
#include <hip/hip_runtime.h>

#define HH 512
#define WW 512
#define PP 8
#define NPTS 100000
#define HID 256
#define TOTAL (HH*WW*PP)   // 2097152

// ---------------- segment-min init ----------------
__global__ void k_init_first(int* first) {
    int i = blockIdx.x*256 + threadIdx.x;
    if (i < NPTS) first[i] = 0x7FFFFFFF;
}

// ---------------- segment-min via atomicMin ----------------
__global__ void k_segmin(const float* __restrict__ z, const int* __restrict__ ids,
                         const int* __restrict__ isTrain, int* __restrict__ first) {
    int i = blockIdx.x*256 + threadIdx.x;   // TOTAL threads
    float thr = (*isTrain) ? 0.2f : 0.0f;
    if (z[i] > thr) atomicMin(&first[ids[i]], i);
}

// ---------------- per-point MLP (6->256->16) ----------------
__global__ void k_mlp(const int* __restrict__ first, const float* __restrict__ z,
                      const float* __restrict__ ray,
                      const float* __restrict__ w1, const float* __restrict__ b1,
                      const float* __restrict__ w2, const float* __restrict__ b2,
                      float* __restrict__ feat) {
    int j = blockIdx.x*256 + threadIdx.x;
    if (j >= NPTS) return;
    int fi = first[j];
    fi = min(fi, TOTAL-1);
    int pix = fi >> 3;
    float zv = z[fi];
    float ox = ray[0], oy = ray[1], oz = ray[2];
    const float* rp = ray + pix*7;
    float dx0 = rp[3], dy0 = rp[4], dz0 = rp[5], cs = rp[6];
    float tt = zv / cs;
    float in6[6] = { ox + tt*dx0, oy + tt*dy0, oz + tt*dz0, dx0, dy0, dz0 };
    float acc[16];
    #pragma unroll
    for (int o=0;o<16;o++) acc[o] = b2[o];
    for (int jh=0; jh<HID; ++jh) {
        float h = b1[jh];
        #pragma unroll
        for (int k=0;k<6;k++) h += in6[k]*w1[k*HID+jh];
        h = fmaxf(h, 0.0f);
        const float4* w2p = (const float4*)(w2 + jh*16);
        float4 q0 = w2p[0], q1 = w2p[1], q2 = w2p[2], q3 = w2p[3];
        acc[0]  += h*q0.x; acc[1]  += h*q0.y; acc[2]  += h*q0.z; acc[3]  += h*q0.w;
        acc[4]  += h*q1.x; acc[5]  += h*q1.y; acc[6]  += h*q1.z; acc[7]  += h*q1.w;
        acc[8]  += h*q2.x; acc[9]  += h*q2.y; acc[10] += h*q2.z; acc[11] += h*q2.w;
        acc[12] += h*q3.x; acc[13] += h*q3.y; acc[14] += h*q3.z; acc[15] += h*q3.w;
    }
    float4* fp = (float4*)(feat + j*16);
    fp[0] = make_float4(acc[0],acc[1],acc[2],acc[3]);
    fp[1] = make_float4(acc[4],acc[5],acc[6],acc[7]);
    fp[2] = make_float4(acc[8],acc[9],acc[10],acc[11]);
    fp[3] = make_float4(acc[12],acc[13],acc[14],acc[15]);
}

// ---------------- gather: fm = mask ? feat[ids] : 0  -> x (512,512,128) ----------------
__global__ void k_gather(const float* __restrict__ z, const int* __restrict__ ids,
                         const int* __restrict__ isTrain,
                         const float* __restrict__ feat, float* __restrict__ x) {
    int i = blockIdx.x*256 + threadIdx.x;   // TOTAL
    float thr = (*isTrain) ? 0.2f : 0.0f;
    bool m = z[i] > thr;
    float4 v0, v1, v2, v3;
    if (m) {
        const float4* fp = (const float4*)(feat + ids[i]*16);
        v0 = fp[0]; v1 = fp[1]; v2 = fp[2]; v3 = fp[3];
    } else {
        v0 = v1 = v2 = v3 = make_float4(0.f,0.f,0.f,0.f);
    }
    float4* xp = (float4*)(x + (size_t)i*16);
    xp[0]=v0; xp[1]=v1; xp[2]=v2; xp[3]=v3;
}

// ---------------- 3x3 conv, Cin=128, Cout=COUT, NHWC, SAME ----------------
// ACT 0: relu(v+b)            (out restrict-free not needed but kept plain)
// ACT 1: aux * sigmoid(v+b)   (aux==out allowed: pointwise same-element)
template<int COUT, int ACT>
__global__ __launch_bounds__(256, 2)
void k_conv3(const float* __restrict__ in, const float* __restrict__ w,
             const float* __restrict__ bias, const float* aux, float* out) {
    constexpr int CPT = COUT/16;           // 8 (COUT=128) or 4 (COUT=64)
    __shared__ __align__(16) float inT[128][10][12];   // transposed tile, 60 KB
    int t = threadIdx.x;
    int bx = blockIdx.x & 63, by = blockIdx.x >> 6;
    int x0 = bx*8, y0 = by*8;

    // stage 10x10x128 input tile (zero-padded), transposed to [c][y][x]
    for (int i = t; i < 12800; i += 256) {
        int c = i & 127;
        int rest = i >> 7;        // 0..99
        int yy = rest / 10;
        int xx = rest - yy*10;
        int gy = y0 + yy - 1, gx = x0 + xx - 1;
        float v = 0.0f;
        if (gy >= 0 && gy < HH && gx >= 0 && gx < WW)
            v = in[((size_t)(gy*WW + gx))*128 + c];
        inT[c][yy][xx] = v;
    }
    __syncthreads();

    int kg = t & 15;          // channel group
    int pg = t >> 4;          // pixel group
    int r  = pg >> 1;         // output row in tile (0..7)
    int px0 = (pg & 1)*4;     // output col base (0 or 4)
    int k0 = kg*CPT;

    float acc[4][CPT];
    #pragma unroll
    for (int i=0;i<4;i++)
        #pragma unroll
        for (int j=0;j<CPT;j++) acc[i][j]=0.f;

    for (int dy=0; dy<3; ++dy) {
        #pragma unroll 2
        for (int c=0; c<128; ++c) {
            const float* p = &inT[c][r+dy][px0];
            float4 wlo = *(const float4*)p;        // 16B aligned
            float2 whi = *(const float2*)(p+4);    // 8B aligned
            float win[6] = {wlo.x, wlo.y, wlo.z, wlo.w, whi.x, whi.y};
            #pragma unroll
            for (int dx=0; dx<3; ++dx) {
                const float* wp = w + ((size_t)((dy*3+dx)*128 + c))*COUT + k0;
                float wk[CPT];
                #pragma unroll
                for (int q=0;q<CPT;q+=4) {
                    float4 wv = *(const float4*)(wp+q);
                    wk[q]=wv.x; wk[q+1]=wv.y; wk[q+2]=wv.z; wk[q+3]=wv.w;
                }
                #pragma unroll
                for (int i=0;i<4;i++) {
                    float a = win[dx+i];
                    #pragma unroll
                    for (int j=0;j<CPT;j++) acc[i][j] += a*wk[j];
                }
            }
        }
    }

    // epilogue
    float bb[CPT];
    #pragma unroll
    for (int j=0;j<CPT;j++) bb[j] = bias[k0+j];
    #pragma unroll
    for (int i=0;i<4;i++) {
        int gy = y0 + r, gx = x0 + px0 + i;
        float* op = out + ((size_t)(gy*WW+gx))*COUT + k0;
        float tmp[CPT];
        if (ACT == 0) {
            #pragma unroll
            for (int j=0;j<CPT;j++) tmp[j] = fmaxf(acc[i][j]+bb[j], 0.f);
        } else {
            const float* ap = aux + ((size_t)(gy*WW+gx))*128 + k0;
            #pragma unroll
            for (int j=0;j<CPT;j++) {
                float v = acc[i][j]+bb[j];
                float s = 1.0f/(1.0f+__expf(-v));
                tmp[j] = ap[j]*s;
            }
        }
        #pragma unroll
        for (int q=0;q<CPT;q+=4)
            *(float4*)(op+q) = make_float4(tmp[q],tmp[q+1],tmp[q+2],tmp[q+3]);
    }
}

// ---------------- final conv 64->3 ----------------
__global__ __launch_bounds__(256)
void k_conv4(const float* __restrict__ u, const float* __restrict__ w,
             const float* __restrict__ bias, float* __restrict__ out) {
    int pix = blockIdx.x*256 + threadIdx.x;    // 262144
    int y = pix >> 9, x = pix & 511;
    float a0 = bias[0], a1 = bias[1], a2 = bias[2];
    #pragma unroll
    for (int dy=0; dy<3; ++dy) {
        int gy = y + dy - 1;
        if (gy < 0 || gy >= HH) continue;
        #pragma unroll
        for (int dx=0; dx<3; ++dx) {
            int gx = x + dx - 1;
            if (gx < 0 || gx >= WW) continue;
            const float* ip = u + ((size_t)(gy*WW+gx))*64;
            const float* wp = w + (dy*3+dx)*64*3;
            #pragma unroll
            for (int c4=0; c4<16; ++c4) {
                float4 iv  = *(const float4*)(ip + c4*4);
                float4 w0  = *(const float4*)(wp + c4*12);
                float4 w1v = *(const float4*)(wp + c4*12+4);
                float4 w2v = *(const float4*)(wp + c4*12+8);
                a0 += iv.x*w0.x + iv.y*w0.w + iv.z*w1v.z + iv.w*w2v.y;
                a1 += iv.x*w0.y + iv.y*w1v.x + iv.z*w1v.w + iv.w*w2v.z;
                a2 += iv.x*w0.z + iv.y*w1v.y + iv.z*w2v.x + iv.w*w2v.w;
            }
        }
    }
    float* op = out + (size_t)pix*3;
    op[0]=a0; op[1]=a1; op[2]=a2;
}

extern "C" void kernel_launch(void* const* d_in, const int* in_sizes, int n_in,
                              void* d_out, int out_size, void* d_ws, size_t ws_size,
                              hipStream_t stream) {
    const float* zbufs = (const float*)d_in[0];
    const int*   idb   = (const int*)d_in[1];
    const float* ray   = (const float*)d_in[2];
    const int*   isTr  = (const int*)d_in[5];
    const float* mlp_w1 = (const float*)d_in[7];
    const float* mlp_b1 = (const float*)d_in[8];
    const float* mlp_w2 = (const float*)d_in[9];
    const float* mlp_b2 = (const float*)d_in[10];
    const float* mpn_w1 = (const float*)d_in[11];
    const float* mpn_b1 = (const float*)d_in[12];
    const float* mpn_w2 = (const float*)d_in[13];
    const float* mpn_b2 = (const float*)d_in[14];
    const float* un_w1  = (const float*)d_in[15];
    const float* un_b1  = (const float*)d_in[16];
    const float* un_w2  = (const float*)d_in[17];
    const float* un_b2  = (const float*)d_in[18];

    // ws layout (256 MiB total):
    //   bufA @ 0        : 128 MiB  (x / fused, 512*512*128 f32)
    //   bufB @ 128 MiB  : 128 MiB  (t1 / u)
    //   first/feat alias the head of bufB (dead before conv1 writes bufB)
    char* ws = (char*)d_ws;
    float* bufA  = (float*)(ws);
    float* bufB  = (float*)(ws + (size_t)128*1024*1024);
    int*   first = (int*)(ws + (size_t)128*1024*1024);
    float* feat  = (float*)(ws + (size_t)129*1024*1024);
    float* img   = (float*)d_out;

    hipLaunchKernelGGL(k_init_first, dim3((NPTS+255)/256), dim3(256), 0, stream, first);
    hipLaunchKernelGGL(k_segmin, dim3(TOTAL/256), dim3(256), 0, stream, zbufs, idb, isTr, first);
    hipLaunchKernelGGL(k_mlp, dim3((NPTS+255)/256), dim3(256), 0, stream,
                       first, zbufs, ray, mlp_w1, mlp_b1, mlp_w2, mlp_b2, feat);
    hipLaunchKernelGGL(k_gather, dim3(TOTAL/256), dim3(256), 0, stream,
                       zbufs, idb, isTr, feat, bufA);
    hipLaunchKernelGGL((k_conv3<128,0>), dim3(4096), dim3(256), 0, stream,
                       bufA, mpn_w1, mpn_b1, nullptr, bufB);
    hipLaunchKernelGGL((k_conv3<128,1>), dim3(4096), dim3(256), 0, stream,
                       bufB, mpn_w2, mpn_b2, bufA, bufA);
    hipLaunchKernelGGL((k_conv3<64,0>), dim3(4096), dim3(256), 0, stream,
                       bufA, un_w1, un_b1, nullptr, bufB);
    hipLaunchKernelGGL(k_conv4, dim3(TOTAL/PP/256), dim3(256), 0, stream,
                       bufB, un_w2, un_b2, img);
}

// Round 3
// 560.243 us; speedup vs baseline: 5.9538x; 5.9538x over previous
//
#include <hip/hip_runtime.h>

#define HH 512
#define WW 512
#define PP 8
#define NPTS 100000
#define HID 256
#define TOTAL (HH*WW*PP)   // 2097152

typedef _Float16 f16x8 __attribute__((ext_vector_type(8)));
typedef float    f32x4 __attribute__((ext_vector_type(4)));

// ---------------- segment-min init ----------------
__global__ void k_init_first(int* first) {
    int i = blockIdx.x*256 + threadIdx.x;
    if (i < NPTS) first[i] = 0x7FFFFFFF;
}

// ---------------- segment-min via atomicMin ----------------
__global__ void k_segmin(const float* __restrict__ z, const int* __restrict__ ids,
                         const int* __restrict__ isTrain, int* __restrict__ first) {
    int i = blockIdx.x*256 + threadIdx.x;   // TOTAL threads
    float thr = (*isTrain) ? 0.2f : 0.0f;
    if (z[i] > thr) atomicMin(&first[ids[i]], i);
}

// ---------------- per-point MLP (6->256->16), fp32 ----------------
__global__ void k_mlp(const int* __restrict__ first, const float* __restrict__ z,
                      const float* __restrict__ ray,
                      const float* __restrict__ w1, const float* __restrict__ b1,
                      const float* __restrict__ w2, const float* __restrict__ b2,
                      float* __restrict__ feat) {
    int j = blockIdx.x*256 + threadIdx.x;
    if (j >= NPTS) return;
    int fi = first[j];
    fi = min(fi, TOTAL-1);
    int pix = fi >> 3;
    float zv = z[fi];
    float ox = ray[0], oy = ray[1], oz = ray[2];
    const float* rp = ray + pix*7;
    float dx0 = rp[3], dy0 = rp[4], dz0 = rp[5], cs = rp[6];
    float tt = zv / cs;
    float in6[6] = { ox + tt*dx0, oy + tt*dy0, oz + tt*dz0, dx0, dy0, dz0 };
    float acc[16];
    #pragma unroll
    for (int o=0;o<16;o++) acc[o] = b2[o];
    for (int jh=0; jh<HID; ++jh) {
        float h = b1[jh];
        #pragma unroll
        for (int k=0;k<6;k++) h += in6[k]*w1[k*HID+jh];
        h = fmaxf(h, 0.0f);
        const float4* w2p = (const float4*)(w2 + jh*16);
        float4 q0 = w2p[0], q1 = w2p[1], q2 = w2p[2], q3 = w2p[3];
        acc[0]  += h*q0.x; acc[1]  += h*q0.y; acc[2]  += h*q0.z; acc[3]  += h*q0.w;
        acc[4]  += h*q1.x; acc[5]  += h*q1.y; acc[6]  += h*q1.z; acc[7]  += h*q1.w;
        acc[8]  += h*q2.x; acc[9]  += h*q2.y; acc[10] += h*q2.z; acc[11] += h*q2.w;
        acc[12] += h*q3.x; acc[13] += h*q3.y; acc[14] += h*q3.z; acc[15] += h*q3.w;
    }
    float4* fp = (float4*)(feat + j*16);
    fp[0] = make_float4(acc[0],acc[1],acc[2],acc[3]);
    fp[1] = make_float4(acc[4],acc[5],acc[6],acc[7]);
    fp[2] = make_float4(acc[8],acc[9],acc[10],acc[11]);
    fp[3] = make_float4(acc[12],acc[13],acc[14],acc[15]);
}

// ---------------- gather: x = mask ? feat[ids] : 0  -> fp16 (512,512,128) ----------------
__global__ void k_gather(const float* __restrict__ z, const int* __restrict__ ids,
                         const int* __restrict__ isTrain,
                         const float* __restrict__ feat, _Float16* __restrict__ xh) {
    int i = blockIdx.x*256 + threadIdx.x;   // TOTAL
    float thr = (*isTrain) ? 0.2f : 0.0f;
    bool m = z[i] > thr;
    float f[16];
    if (m) {
        const float4* fp = (const float4*)(feat + ids[i]*16);
        float4 v0=fp[0], v1=fp[1], v2=fp[2], v3=fp[3];
        f[0]=v0.x; f[1]=v0.y; f[2]=v0.z; f[3]=v0.w;
        f[4]=v1.x; f[5]=v1.y; f[6]=v1.z; f[7]=v1.w;
        f[8]=v2.x; f[9]=v2.y; f[10]=v2.z; f[11]=v2.w;
        f[12]=v3.x; f[13]=v3.y; f[14]=v3.z; f[15]=v3.w;
    } else {
        #pragma unroll
        for (int j=0;j<16;j++) f[j]=0.f;
    }
    f16x8 h0, h1;
    #pragma unroll
    for (int j=0;j<8;j++){ h0[j]=(_Float16)f[j]; h1[j]=(_Float16)f[j+8]; }
    *(f16x8*)(xh + (size_t)i*16)     = h0;
    *(f16x8*)(xh + (size_t)i*16 + 8) = h1;
}

// ---------------- weight convert: [3,3,128,COUT] f32 -> [9][4][COUT][32] f16 ----------------
__global__ void k_wcvt(const float* __restrict__ w, _Float16* __restrict__ wt, int COUT) {
    int i = blockIdx.x*256 + threadIdx.x;
    if (i >= 9*128*COUT) return;
    int co = i % COUT; int tmp = i / COUT;
    int ci = tmp & 127; int tt = tmp >> 7;
    wt[((size_t)(tt*4 + (ci>>5))*COUT + co)*32 + (ci&31)] = (_Float16)w[i];
}

// ---------------- fp16 MFMA implicit-GEMM 3x3 conv ----------------
// block: 8y x 16x pixel tile, all COUT. 4 waves as 2(wm) x 2(wn).
// ACT 0: relu -> f16 out.  ACT 1: aux * sigmoid -> f16 out.
template<int COUT, int ACT>
__global__ __launch_bounds__(256, 2)
void k_convmfma(const _Float16* __restrict__ in, const _Float16* __restrict__ wt,
                const float* __restrict__ bias, const _Float16* aux,
                _Float16* __restrict__ out)
{
    constexpr int FN = COUT/32;                 // acc frags in N per wave
    __shared__ __align__(16) _Float16 smem[23040];   // 46080 B: A-tile, then out-tile
    int t = threadIdx.x;
    int bx = blockIdx.x & 31, by = blockIdx.x >> 5;
    int x0 = bx*16, y0 = by*8;

    // stage 10x18x128 f16 nbhd; slot (16B unit of 8 ch) swizzled with ^ (x&7)
    for (int u = t; u < 2880; u += 256) {
        int pix = u >> 4, slot = u & 15;
        int yn = pix / 18, xn = pix - yn*18;
        int gy = y0 + yn - 1, gx = x0 + xn - 1;
        uint4 v = make_uint4(0u,0u,0u,0u);
        if (gy >= 0 && gy < HH && gx >= 0 && gx < WW)
            v = *(const uint4*)(in + ((size_t)(gy*WW+gx))*128 + slot*8);
        int ps = slot ^ (xn & 7);
        *(uint4*)(&smem[pix*128 + ps*8]) = v;
    }
    __syncthreads();

    int lane = t & 63, wid = t >> 6;
    int wm = wid >> 1, wn = wid & 1;
    int lx = lane & 15, sg = lane >> 4;

    f32x4 acc[4][FN];
    #pragma unroll
    for (int i=0;i<4;i++)
        #pragma unroll
        for (int j=0;j<FN;j++) acc[i][j] = (f32x4){0.f,0.f,0.f,0.f};

    const _Float16* wbase = wt + (size_t)(wn*(COUT/2) + lx)*32 + sg*8;

    #pragma unroll 1
    for (int dy=0; dy<3; ++dy) {
        #pragma unroll
        for (int dx=0; dx<3; ++dx) {
            int tt = dy*3+dx;
            int xn = lx + dx;
            int xk = xn & 7;
            #pragma unroll
            for (int cc=0; cc<4; ++cc) {
                f16x8 b[FN];
                #pragma unroll
                for (int fn=0; fn<FN; ++fn)
                    b[fn] = *(const f16x8*)(wbase + (size_t)((tt*4+cc)*COUT + fn*16)*32);
                #pragma unroll
                for (int fm=0; fm<4; ++fm) {
                    int yn = wm*4 + fm + dy;
                    int slot = (cc*4 + sg) ^ xk;
                    f16x8 a = *(const f16x8*)(&smem[((yn*18 + xn)*16 + slot)*8]);
                    #pragma unroll
                    for (int fn=0; fn<FN; ++fn)
                        acc[fm][fn] = __builtin_amdgcn_mfma_f32_16x16x32_f16(a, b[fn], acc[fm][fn], 0,0,0);
                }
            }
        }
    }
    __syncthreads();

    // epilogue: acc -> smem[8][16][COUT] f16 (D frag: m=sg*4+r -> x, n=lx -> cout)
    #pragma unroll
    for (int fm=0; fm<4; ++fm) {
        int y = wm*4 + fm;
        #pragma unroll
        for (int fn=0; fn<FN; ++fn) {
            int cout = wn*(COUT/2) + fn*16 + lx;
            float bb = bias[cout];
            #pragma unroll
            for (int r=0; r<4; ++r) {
                int x = sg*4 + r;
                float v = acc[fm][fn][r] + bb;
                float res;
                if (ACT == 0) {
                    res = fmaxf(v, 0.f);
                } else {
                    float xa = (float)aux[((size_t)((y0+y)*WW + x0+x))*128 + cout];
                    res = xa / (1.f + __expf(-v));
                }
                smem[(y*16 + x)*COUT + cout] = (_Float16)res;
            }
        }
    }
    __syncthreads();

    // coalesced linear store of the 8x16xCOUT tile
    constexpr int UNITS = 128*COUT/8;   // 16B units
    for (int u = t; u < UNITS; u += 256) {
        int byte = u*16;
        int y = byte / (16*COUT*2);
        int rest = byte - y*(16*COUT*2);
        uint4 v = *(const uint4*)((const char*)smem + byte);
        *(uint4*)((char*)out + ((size_t)((y0+y)*WW + x0)*COUT)*2 + rest) = v;
    }
}

// ---------------- final conv 64->3, fp32 accum from f16 input ----------------
__global__ __launch_bounds__(256)
void k_conv4(const _Float16* __restrict__ u, const float* __restrict__ w,
             const float* __restrict__ bias, float* __restrict__ out) {
    int pix = blockIdx.x*256 + threadIdx.x;    // 262144
    int y = pix >> 9, x = pix & 511;
    float a0 = bias[0], a1 = bias[1], a2 = bias[2];
    for (int dy=0; dy<3; ++dy) {
        int gy = y + dy - 1;
        if (gy < 0 || gy >= HH) continue;
        for (int dx=0; dx<3; ++dx) {
            int gx = x + dx - 1;
            if (gx < 0 || gx >= WW) continue;
            const _Float16* ip = u + (size_t)(gy*WW+gx)*64;
            const float* wp = w + (dy*3+dx)*192;
            #pragma unroll
            for (int c8=0; c8<8; ++c8) {
                f16x8 v = *(const f16x8*)(ip + c8*8);
                #pragma unroll
                for (int e=0; e<8; ++e) {
                    float f = (float)v[e];
                    const float* q = wp + (c8*8+e)*3;
                    a0 += f*q[0]; a1 += f*q[1]; a2 += f*q[2];
                }
            }
        }
    }
    float* op = out + (size_t)pix*3;
    op[0]=a0; op[1]=a1; op[2]=a2;
}

extern "C" void kernel_launch(void* const* d_in, const int* in_sizes, int n_in,
                              void* d_out, int out_size, void* d_ws, size_t ws_size,
                              hipStream_t stream) {
    const float* zbufs = (const float*)d_in[0];
    const int*   idb   = (const int*)d_in[1];
    const float* ray   = (const float*)d_in[2];
    const int*   isTr  = (const int*)d_in[5];
    const float* mlp_w1 = (const float*)d_in[7];
    const float* mlp_b1 = (const float*)d_in[8];
    const float* mlp_w2 = (const float*)d_in[9];
    const float* mlp_b2 = (const float*)d_in[10];
    const float* mpn_w1 = (const float*)d_in[11];
    const float* mpn_b1 = (const float*)d_in[12];
    const float* mpn_w2 = (const float*)d_in[13];
    const float* mpn_b2 = (const float*)d_in[14];
    const float* un_w1  = (const float*)d_in[15];
    const float* un_b1  = (const float*)d_in[16];
    const float* un_w2  = (const float*)d_in[17];
    const float* un_b2  = (const float*)d_in[18];

    // ws layout:
    //   bufXh  @ 0     : 64 MiB  f16 x (and aux for conv2)
    //   bufT   @ 64M   : 64 MiB  f16 t1, later u (conv3 out, 32 MiB)
    //   bufF   @ 128M  : 64 MiB  f16 fused (conv2 out)
    //   scratch @192M  : first (0.4M), feat (6.4M), wt1/wt2/wt3 (~0.8M)
    char* ws = (char*)d_ws;
    _Float16* bufXh = (_Float16*)(ws);
    _Float16* bufT  = (_Float16*)(ws + (size_t)64*1024*1024);
    _Float16* bufF  = (_Float16*)(ws + (size_t)128*1024*1024);
    char* sc = ws + (size_t)192*1024*1024;
    int*      first = (int*)(sc);
    float*    feat  = (float*)(sc + (size_t)1*1024*1024);
    _Float16* wt1   = (_Float16*)(sc + (size_t)8*1024*1024);
    _Float16* wt2   = (_Float16*)(sc + (size_t)9*1024*1024);
    _Float16* wt3   = (_Float16*)(sc + (size_t)10*1024*1024);
    float* img = (float*)d_out;

    hipLaunchKernelGGL(k_init_first, dim3((NPTS+255)/256), dim3(256), 0, stream, first);
    hipLaunchKernelGGL(k_segmin, dim3(TOTAL/256), dim3(256), 0, stream, zbufs, idb, isTr, first);
    hipLaunchKernelGGL(k_mlp, dim3((NPTS+255)/256), dim3(256), 0, stream,
                       first, zbufs, ray, mlp_w1, mlp_b1, mlp_w2, mlp_b2, feat);
    hipLaunchKernelGGL(k_wcvt, dim3((9*128*128+255)/256), dim3(256), 0, stream, mpn_w1, wt1, 128);
    hipLaunchKernelGGL(k_wcvt, dim3((9*128*128+255)/256), dim3(256), 0, stream, mpn_w2, wt2, 128);
    hipLaunchKernelGGL(k_wcvt, dim3((9*128*64+255)/256), dim3(256), 0, stream, un_w1, wt3, 64);
    hipLaunchKernelGGL(k_gather, dim3(TOTAL/256), dim3(256), 0, stream,
                       zbufs, idb, isTr, feat, bufXh);
    hipLaunchKernelGGL((k_convmfma<128,0>), dim3(2048), dim3(256), 0, stream,
                       bufXh, wt1, mpn_b1, (const _Float16*)nullptr, bufT);
    hipLaunchKernelGGL((k_convmfma<128,1>), dim3(2048), dim3(256), 0, stream,
                       bufT, wt2, mpn_b2, bufXh, bufF);
    hipLaunchKernelGGL((k_convmfma<64,0>), dim3(2048), dim3(256), 0, stream,
                       bufF, wt3, un_b1, (const _Float16*)nullptr, bufT);
    hipLaunchKernelGGL(k_conv4, dim3(TOTAL/PP/256), dim3(256), 0, stream,
                       bufT, un_w2, un_b2, img);
}

// Round 8
// 537.995 us; speedup vs baseline: 6.2000x; 1.0414x over previous
//
#include <hip/hip_runtime.h>

#define HH 512
#define WW 512
#define PP 8
#define NPTS 100000
#define HID 256
#define TOTAL (HH*WW*PP)   // 2097152

typedef _Float16 f16x8 __attribute__((ext_vector_type(8)));
typedef _Float16 f16x4 __attribute__((ext_vector_type(4)));
typedef float    f32x4 __attribute__((ext_vector_type(4)));
typedef __attribute__((address_space(1))) const unsigned int gu32;
typedef __attribute__((address_space(3))) unsigned int lu32;

// ---------------- init: first[] = INT_MAX, zero page for halo DMA ----------------
__global__ void k_init_first(int* first, float4* zpad) {
    int i = blockIdx.x*256 + threadIdx.x;
    if (i < NPTS) first[i] = 0x7FFFFFFF;
    if (i < 64) zpad[i] = make_float4(0.f,0.f,0.f,0.f);
}

// ---------------- segment-min via atomicMin ----------------
__global__ void k_segmin(const float* __restrict__ z, const int* __restrict__ ids,
                         const int* __restrict__ isTrain, int* __restrict__ first) {
    int i = blockIdx.x*256 + threadIdx.x;   // TOTAL threads
    float thr = (*isTrain) ? 0.2f : 0.0f;
    if (z[i] > thr) atomicMin(&first[ids[i]], i);
}

// ---------------- per-point MLP (6->256->16), fp32 ----------------
__global__ void k_mlp(const int* __restrict__ first, const float* __restrict__ z,
                      const float* __restrict__ ray,
                      const float* __restrict__ w1, const float* __restrict__ b1,
                      const float* __restrict__ w2, const float* __restrict__ b2,
                      float* __restrict__ feat) {
    int j = blockIdx.x*256 + threadIdx.x;
    if (j >= NPTS) return;
    int fi = first[j];
    fi = min(fi, TOTAL-1);
    int pix = fi >> 3;
    float zv = z[fi];
    float ox = ray[0], oy = ray[1], oz = ray[2];
    const float* rp = ray + pix*7;
    float dx0 = rp[3], dy0 = rp[4], dz0 = rp[5], cs = rp[6];
    float tt = zv / cs;
    float in6[6] = { ox + tt*dx0, oy + tt*dy0, oz + tt*dz0, dx0, dy0, dz0 };
    float acc[16];
    #pragma unroll
    for (int o=0;o<16;o++) acc[o] = b2[o];
    for (int jh=0; jh<HID; ++jh) {
        float h = b1[jh];
        #pragma unroll
        for (int k=0;k<6;k++) h += in6[k]*w1[k*HID+jh];
        h = fmaxf(h, 0.0f);
        const float4* w2p = (const float4*)(w2 + jh*16);
        float4 q0 = w2p[0], q1 = w2p[1], q2 = w2p[2], q3 = w2p[3];
        acc[0]  += h*q0.x; acc[1]  += h*q0.y; acc[2]  += h*q0.z; acc[3]  += h*q0.w;
        acc[4]  += h*q1.x; acc[5]  += h*q1.y; acc[6]  += h*q1.z; acc[7]  += h*q1.w;
        acc[8]  += h*q2.x; acc[9]  += h*q2.y; acc[10] += h*q2.z; acc[11] += h*q2.w;
        acc[12] += h*q3.x; acc[13] += h*q3.y; acc[14] += h*q3.z; acc[15] += h*q3.w;
    }
    float4* fp = (float4*)(feat + j*16);
    fp[0] = make_float4(acc[0],acc[1],acc[2],acc[3]);
    fp[1] = make_float4(acc[4],acc[5],acc[6],acc[7]);
    fp[2] = make_float4(acc[8],acc[9],acc[10],acc[11]);
    fp[3] = make_float4(acc[12],acc[13],acc[14],acc[15]);
}

// ---------------- gather: x = mask ? feat[ids] : 0  -> fp16 (512,512,128) ----------------
__global__ void k_gather(const float* __restrict__ z, const int* __restrict__ ids,
                         const int* __restrict__ isTrain,
                         const float* __restrict__ feat, _Float16* __restrict__ xh) {
    int i = blockIdx.x*256 + threadIdx.x;   // TOTAL
    float thr = (*isTrain) ? 0.2f : 0.0f;
    bool m = z[i] > thr;
    float f[16];
    if (m) {
        const float4* fp = (const float4*)(feat + ids[i]*16);
        float4 v0=fp[0], v1=fp[1], v2=fp[2], v3=fp[3];
        f[0]=v0.x; f[1]=v0.y; f[2]=v0.z; f[3]=v0.w;
        f[4]=v1.x; f[5]=v1.y; f[6]=v1.z; f[7]=v1.w;
        f[8]=v2.x; f[9]=v2.y; f[10]=v2.z; f[11]=v2.w;
        f[12]=v3.x; f[13]=v3.y; f[14]=v3.z; f[15]=v3.w;
    } else {
        #pragma unroll
        for (int j=0;j<16;j++) f[j]=0.f;
    }
    f16x8 h0, h1;
    #pragma unroll
    for (int j=0;j<8;j++){ h0[j]=(_Float16)f[j]; h1[j]=(_Float16)f[j+8]; }
    *(f16x8*)(xh + (size_t)i*16)     = h0;
    *(f16x8*)(xh + (size_t)i*16 + 8) = h1;
}

// ---------------- weight convert: [3,3,128,COUT] f32 -> [9][4][COUT][32] f16 ----------------
__global__ void k_wcvt(const float* __restrict__ w, _Float16* __restrict__ wt, int COUT) {
    int i = blockIdx.x*256 + threadIdx.x;
    if (i >= 9*128*COUT) return;
    int co = i % COUT; int tmp = i / COUT;
    int ci = tmp & 127; int tt = tmp >> 7;
    wt[((size_t)(tt*4 + (ci>>5))*COUT + co)*32 + (ci&31)] = (_Float16)w[i];
}

// ---------------- fp16 MFMA implicit-GEMM 3x3 conv (flipped operands) ----------------
// block: 8y x 16x pixel tile, all COUT. 4 waves: wm (y half) x wn (cout half).
// mfma(A=weights[m=cout][k=cin], B=input[k=cin][n=x]) -> D[row=cout][col=x]
// => lane holds 4 CONSECUTIVE couts per frag -> direct f16x4 global stores, no LDS epilogue.
// ACT 0: relu -> f16 out.  ACT 1: aux * sigmoid -> f16 out.
template<int COUT, int ACT>
__global__ __launch_bounds__(256, 3)
void k_convmfma(const _Float16* __restrict__ in, const _Float16* __restrict__ wt,
                const float* __restrict__ bias, const _Float16* aux,
                _Float16* __restrict__ out, const _Float16* __restrict__ zpad)
{
    constexpr int FN = COUT/32;                      // cout frags per wave
    __shared__ __align__(16) _Float16 smem[23040];   // 46080 B = 10*18 pixels * 16 slots * 16B
    int t = threadIdx.x;
    int bx = blockIdx.x & 31, by = blockIdx.x >> 5;
    int x0 = bx*16, y0 = by*8;

    // stage 10x18x128 f16 nbhd via global_load_lds (linear LDS dest, swizzled SOURCE):
    // LDS position (pix, p) holds global slot p ^ (xn&7); OOB halo lanes read zero page.
    for (int u = t; u < 2880; u += 256) {
        int pix = u >> 4, p = u & 15;
        int yn = pix / 18, xn = pix - yn*18;
        int gy = y0 + yn - 1, gx = x0 + xn - 1;
        int slot = p ^ (xn & 7);
        const _Float16* src = (gy >= 0 && gy < HH && gx >= 0 && gx < WW)
            ? in + ((size_t)(gy*WW+gx))*128 + slot*8
            : zpad;
        __builtin_amdgcn_global_load_lds((gu32*)src, (lu32*)&smem[u*8], 16, 0, 0);
    }
    __syncthreads();

    int lane = t & 63, wid = t >> 6;
    int wm = wid >> 1, wn = wid & 1;
    int lx = lane & 15, sg = lane >> 4;

    f32x4 acc[4][FN];   // [yy][cout-frag]
    #pragma unroll
    for (int i=0;i<4;i++)
        #pragma unroll
        for (int j=0;j<FN;j++) acc[i][j] = (f32x4){0.f,0.f,0.f,0.f};

    // A-frag (weights): m = lane&15 -> cout, k = sg*8+j -> cin within 32-chunk
    const _Float16* wbase = wt + (size_t)(wn*(COUT/2) + lx)*32 + sg*8;

    #pragma unroll 1
    for (int dy=0; dy<3; ++dy) {
        #pragma unroll
        for (int dx=0; dx<3; ++dx) {
            int tt = dy*3+dx;
            int xn = lx + dx;
            int xk = xn & 7;
            #pragma unroll
            for (int cc=0; cc<4; ++cc) {
                f16x8 b[FN];
                #pragma unroll
                for (int cf=0; cf<FN; ++cf)
                    b[cf] = *(const f16x8*)(wbase + (size_t)((tt*4+cc)*COUT + cf*16)*32);
                #pragma unroll
                for (int yy=0; yy<4; ++yy) {
                    int yn = wm*4 + yy + dy;
                    int slot = (cc*4 + sg) ^ xk;
                    f16x8 a = *(const f16x8*)(&smem[((yn*18 + xn)*16 + slot)*8]);
                    #pragma unroll
                    for (int cf=0; cf<FN; ++cf)
                        acc[yy][cf] = __builtin_amdgcn_mfma_f32_16x16x32_f16(b[cf], a, acc[yy][cf], 0,0,0);
                }
            }
        }
    }

    // epilogue: D row = cout = sg*4 + r (4 consecutive), col = pixel x = lx
    #pragma unroll
    for (int yy=0; yy<4; ++yy) {
        int gy = y0 + wm*4 + yy;
        size_t prow = ((size_t)gy*WW + x0 + lx);
        #pragma unroll
        for (int cf=0; cf<FN; ++cf) {
            int c0 = wn*(COUT/2) + cf*16 + sg*4;
            f16x4 v;
            if (ACT == 0) {
                #pragma unroll
                for (int r=0;r<4;r++)
                    v[r] = (_Float16)fmaxf(acc[yy][cf][r] + bias[c0+r], 0.f);
            } else {
                f16x4 av = *(const f16x4*)(aux + prow*128 + c0);
                #pragma unroll
                for (int r=0;r<4;r++) {
                    float s = acc[yy][cf][r] + bias[c0+r];
                    v[r] = (_Float16)((float)av[r] / (1.f + __expf(-s)));
                }
            }
            *(f16x4*)(out + prow*COUT + c0) = v;
        }
    }
}

// ---------------- final conv 64->3, fp32 accum from f16 input ----------------
__global__ __launch_bounds__(256)
void k_conv4(const _Float16* __restrict__ u, const float* __restrict__ w,
             const float* __restrict__ bias, float* __restrict__ out) {
    int pix = blockIdx.x*256 + threadIdx.x;    // 262144
    int y = pix >> 9, x = pix & 511;
    float a0 = bias[0], a1 = bias[1], a2 = bias[2];
    for (int dy=0; dy<3; ++dy) {
        int gy = y + dy - 1;
        if (gy < 0 || gy >= HH) continue;
        for (int dx=0; dx<3; ++dx) {
            int gx = x + dx - 1;
            if (gx < 0 || gx >= WW) continue;
            const _Float16* ip = u + (size_t)(gy*WW+gx)*64;
            const float* wp = w + (dy*3+dx)*192;
            #pragma unroll
            for (int c8=0; c8<8; ++c8) {
                f16x8 v = *(const f16x8*)(ip + c8*8);
                #pragma unroll
                for (int e=0; e<8; ++e) {
                    float f = (float)v[e];
                    const float* q = wp + (c8*8+e)*3;
                    a0 += f*q[0]; a1 += f*q[1]; a2 += f*q[2];
                }
            }
        }
    }
    float* op = out + (size_t)pix*3;
    op[0]=a0; op[1]=a1; op[2]=a2;
}

extern "C" void kernel_launch(void* const* d_in, const int* in_sizes, int n_in,
                              void* d_out, int out_size, void* d_ws, size_t ws_size,
                              hipStream_t stream) {
    const float* zbufs = (const float*)d_in[0];
    const int*   idb   = (const int*)d_in[1];
    const float* ray   = (const float*)d_in[2];
    const int*   isTr  = (const int*)d_in[5];
    const float* mlp_w1 = (const float*)d_in[7];
    const float* mlp_b1 = (const float*)d_in[8];
    const float* mlp_w2 = (const float*)d_in[9];
    const float* mlp_b2 = (const float*)d_in[10];
    const float* mpn_w1 = (const float*)d_in[11];
    const float* mpn_b1 = (const float*)d_in[12];
    const float* mpn_w2 = (const float*)d_in[13];
    const float* mpn_b2 = (const float*)d_in[14];
    const float* un_w1  = (const float*)d_in[15];
    const float* un_b1  = (const float*)d_in[16];
    const float* un_w2  = (const float*)d_in[17];
    const float* un_b2  = (const float*)d_in[18];

    // ws layout:
    //   bufXh  @ 0     : 64 MiB  f16 x (aux for conv2)
    //   bufT   @ 64M   : 64 MiB  f16 t1, later u (conv3 out)
    //   bufF   @ 128M  : 64 MiB  f16 fused (conv2 out)
    //   scratch @192M  : first, feat, wt1/wt2/wt3, zero page
    char* ws = (char*)d_ws;
    _Float16* bufXh = (_Float16*)(ws);
    _Float16* bufT  = (_Float16*)(ws + (size_t)64*1024*1024);
    _Float16* bufF  = (_Float16*)(ws + (size_t)128*1024*1024);
    char* sc = ws + (size_t)192*1024*1024;
    int*      first = (int*)(sc);
    float*    feat  = (float*)(sc + (size_t)1*1024*1024);
    _Float16* wt1   = (_Float16*)(sc + (size_t)8*1024*1024);
    _Float16* wt2   = (_Float16*)(sc + (size_t)9*1024*1024);
    _Float16* wt3   = (_Float16*)(sc + (size_t)10*1024*1024);
    float4*   zpad  = (float4*)(sc + (size_t)11*1024*1024);
    float* img = (float*)d_out;

    hipLaunchKernelGGL(k_init_first, dim3((NPTS+255)/256), dim3(256), 0, stream, first, zpad);
    hipLaunchKernelGGL(k_segmin, dim3(TOTAL/256), dim3(256), 0, stream, zbufs, idb, isTr, first);
    hipLaunchKernelGGL(k_mlp, dim3((NPTS+255)/256), dim3(256), 0, stream,
                       first, zbufs, ray, mlp_w1, mlp_b1, mlp_w2, mlp_b2, feat);
    hipLaunchKernelGGL(k_wcvt, dim3((9*128*128+255)/256), dim3(256), 0, stream, mpn_w1, wt1, 128);
    hipLaunchKernelGGL(k_wcvt, dim3((9*128*128+255)/256), dim3(256), 0, stream, mpn_w2, wt2, 128);
    hipLaunchKernelGGL(k_wcvt, dim3((9*128*64+255)/256), dim3(256), 0, stream, un_w1, wt3, 64);
    hipLaunchKernelGGL(k_gather, dim3(TOTAL/256), dim3(256), 0, stream,
                       zbufs, idb, isTr, feat, bufXh);
    hipLaunchKernelGGL((k_convmfma<128,0>), dim3(2048), dim3(256), 0, stream,
                       bufXh, wt1, mpn_b1, (const _Float16*)nullptr, bufT, (const _Float16*)zpad);
    hipLaunchKernelGGL((k_convmfma<128,1>), dim3(2048), dim3(256), 0, stream,
                       bufT, wt2, mpn_b2, bufXh, bufF, (const _Float16*)zpad);
    hipLaunchKernelGGL((k_convmfma<64,0>), dim3(2048), dim3(256), 0, stream,
                       bufF, wt3, un_b1, (const _Float16*)nullptr, bufT, (const _Float16*)zpad);
    hipLaunchKernelGGL(k_conv4, dim3(TOTAL/PP/256), dim3(256), 0, stream,
                       bufT, un_w2, un_b2, img);
}